// Round 9
// baseline (577.000 us; speedup 1.0000x reference)
//
#include <hip/hip_runtime.h>
#include <hip/hip_bf16.h>

// CoarseGraining: y[i,b] = heg[b] * sum_j exp(-beta[j,b] * d2(i,j)) * wrho[j]
// N = M = 8192, NB = 16, WIDTH = 32. Inputs float32, output float32 (proven R5).
// R5: global-load pairs kernel, 322us, VALUBusy 33%, 1024 blocks (4 waves/SIMD).
// R8: LDS-staged tile, 350us, VALUBusy 31% -> loads were NOT the bottleneck;
//     kernel is stall-bound with too few waves (grid-limited occupancy).
// R9: JC 256->128 => 2048 blocks = 8 blocks/CU = 32 waves/CU; direct loads
//     (R5 form, the faster variant); __launch_bounds__(256,8) keeps VGPR<=64.
// Builtins: exp2 = __builtin_amdgcn_exp2f, log2 = __builtin_amdgcn_logf.

#define N_PTS 8192
#define M_PTS 8192
#define NBASIS 16
#define WIDTH 32
#define TI 256      // i-points per block (== blockDim.x)
#define JC 128      // j-points per block (j-chunk)

__device__ __forceinline__ float exp2_hw(float x) { return __builtin_amdgcn_exp2f(x); }
__device__ __forceinline__ float log2_hw(float x) { return __builtin_amdgcn_logf(x); }

__device__ __forceinline__ float fast_tanh(float z) {
    float a = fabsf(z);
    float t = __expf(-2.0f * a);          // v_exp_f32
    float r = (1.0f - t) / (1.0f + t);
    return copysignf(r, z);
}

__device__ __forceinline__ float log_cosh_f(float x) {
    float a = fabsf(x);
    // log(cosh(x)) = |x| + log1p(exp(-2|x|)) - log(2)
    return a + __logf(1.0f + __expf(-2.0f * a)) - 0.6931471805599453f;
}

// ---------------- Stage 1: per-source-point quantities ----------------
// cw[j]           = (cx, cy, cz, wrho)
// betaneg[j*16+b] = -log2(e) * beta[j,b]  (so exp(-beta*d2) = exp2(bn*d2))
// hegf[0..15]     = log_cosh(embed(0))^1.5
__global__ __launch_bounds__(256)
void cg_prep(const float* __restrict__ rho,
             const float* __restrict__ gamma,
             const float* __restrict__ coords,
             const float* __restrict__ weights,
             const float* __restrict__ w1,
             const float* __restrict__ b1,
             const float* __restrict__ w2,
             const float* __restrict__ b2,
             float4* __restrict__ cw,
             float* __restrict__ betaneg,
             float* __restrict__ hegf)
{
    const float PI_F = 3.14159265358979323846f;
    const float LOG2E = 1.4426950408889634f;

    __shared__ float s_w1[WIDTH], s_b1[WIDTH], s_w2[WIDTH * NBASIS], s_b2[NBASIS];
    int t = threadIdx.x;
    if (t < WIDTH) { s_w1[t] = w1[t]; s_b1[t] = b1[t]; }
    if (t < NBASIS) s_b2[t] = b2[t];
    s_w2[t] = w2[t];
    s_w2[t + 256] = w2[t + 256];
    __syncthreads();

    int j = blockIdx.x * blockDim.x + t;
    if (j < N_PTS) {
        float r = rho[j];
        float g = gamma[j];
        const float c83 = 38.28312007948569f;              // 4*(3*pi^2)^(2/3)
        float r83 = exp2_hw(2.6666666667f * log2_hw(r));   // r^(8/3)
        float s2 = g / (c83 * r83);
        float x = __logf(s2 + 1e-4f);

        float emb[NBASIS];
        #pragma unroll
        for (int b = 0; b < NBASIS; ++b) emb[b] = s_b2[b];
        #pragma unroll 4
        for (int w = 0; w < WIDTH; ++w) {
            float h = fast_tanh(fmaf(x, s_w1[w], s_b1[w]));
            #pragma unroll
            for (int b = 0; b < NBASIS; ++b)
                emb[b] = fmaf(h, s_w2[w * NBASIS + b], emb[b]);
        }
        float pref = PI_F * exp2_hw(0.6666666667f * log2_hw(0.5f * r));
        #pragma unroll
        for (int b = 0; b < NBASIS; ++b)
            betaneg[j * NBASIS + b] = -LOG2E * pref * log_cosh_f(emb[b]);

        cw[j] = make_float4(coords[j * 3 + 0],
                            coords[j * 3 + 1],
                            coords[j * 3 + 2],
                            weights[j] * r);
    }

    if (blockIdx.x == 0 && t == 0) {
        float emb0[NBASIS];
        #pragma unroll
        for (int b = 0; b < NBASIS; ++b) emb0[b] = s_b2[b];
        for (int w = 0; w < WIDTH; ++w) {
            float h = fast_tanh(s_b1[w]);   // x = 0
            #pragma unroll
            for (int b = 0; b < NBASIS; ++b)
                emb0[b] = fmaf(h, s_w2[w * NBASIS + b], emb0[b]);
        }
        #pragma unroll
        for (int b = 0; b < NBASIS; ++b) {
            float lc = fmaxf(log_cosh_f(emb0[b]), 0.0f);
            hegf[b] = lc * sqrtf(lc);       // lc^1.5
        }
    }
}

// ---------------- Stage 2: all-pairs accumulation ----------------
// grid = (M/TI, N/JC) = (32, 64) = 2048 blocks -> 8 blocks/CU, 32 waves/CU.
// Wave-uniform cw/bn loads scalarize to s_load (R5 evidence: VGPR=20/SGPR=48).
__global__ __launch_bounds__(256, 8)
void cg_pairs(const float* __restrict__ oc,
              const float4* __restrict__ cw,
              const float* __restrict__ betaneg,
              float* __restrict__ ypart)
{
    int i = blockIdx.x * TI + threadIdx.x;
    float ox = oc[i * 3 + 0];
    float oy = oc[i * 3 + 1];
    float oz = oc[i * 3 + 2];

    float acc[NBASIS];
    #pragma unroll
    for (int b = 0; b < NBASIS; ++b) acc[b] = 0.0f;

    int j0 = blockIdx.y * JC;
    for (int j = j0; j < j0 + JC; ++j) {
        float4 c = cw[j];                    // wave-uniform load
        float dx = ox - c.x;
        float dy = oy - c.y;
        float dz = oz - c.z;
        float d2 = fmaf(dx, dx, fmaf(dy, dy, dz * dz));
        const float4* bn = (const float4*)&betaneg[j * NBASIS];  // uniform, 64 B
        #pragma unroll
        for (int q = 0; q < 4; ++q) {
            float4 b4 = bn[q];
            float e0 = exp2_hw(b4.x * d2);
            float e1 = exp2_hw(b4.y * d2);
            float e2 = exp2_hw(b4.z * d2);
            float e3 = exp2_hw(b4.w * d2);
            acc[q * 4 + 0] = fmaf(e0, c.w, acc[q * 4 + 0]);
            acc[q * 4 + 1] = fmaf(e1, c.w, acc[q * 4 + 1]);
            acc[q * 4 + 2] = fmaf(e2, c.w, acc[q * 4 + 2]);
            acc[q * 4 + 3] = fmaf(e3, c.w, acc[q * 4 + 3]);
        }
    }
    #pragma unroll
    for (int b = 0; b < NBASIS; ++b)
        atomicAdd(&ypart[i * NBASIS + b], acc[b]);
}

// ---------------- Stage 3: scale, float32 output ----------------
__global__ __launch_bounds__(256)
void cg_finalize(const float* __restrict__ ypart,
                 const float* __restrict__ hegf,
                 float* __restrict__ out)
{
    int idx = blockIdx.x * blockDim.x + threadIdx.x;   // [0, M*NB)
    out[idx] = ypart[idx] * hegf[idx & (NBASIS - 1)];
}

extern "C" void kernel_launch(void* const* d_in, const int* in_sizes, int n_in,
                              void* d_out, int out_size, void* d_ws, size_t ws_size,
                              hipStream_t stream) {
    const float* rho        = (const float*)d_in[0];
    const float* gamma      = (const float*)d_in[1];
    const float* coords     = (const float*)d_in[2];
    const float* weights    = (const float*)d_in[3];
    const float* out_coords = (const float*)d_in[4];
    const float* w1         = (const float*)d_in[5];
    const float* b1         = (const float*)d_in[6];
    const float* w2         = (const float*)d_in[7];
    const float* b2         = (const float*)d_in[8];

    char* ws = (char*)d_ws;
    // ws layout (1.1253 MB total — proven mapped in R1/R5):
    //   cw      : N * float4           = 128 KiB  @ 0
    //   betaneg : N * 16 * float       = 512 KiB  @ 128K
    //   hegf    : 16 * float (256B)               @ 640K
    //   ypart   : M * 16 * float       = 512 KiB  @ 640K + 256
    float4* cw      = (float4*)(ws);
    float*  betaneg = (float*) (ws + (128 << 10));
    float*  hegf    = (float*) (ws + (640 << 10));
    float*  ypart   = (float*) (ws + (640 << 10) + 256);

    (void)hipMemsetAsync(ypart, 0, (size_t)M_PTS * NBASIS * sizeof(float), stream);

    cg_prep<<<N_PTS / 256, 256, 0, stream>>>(rho, gamma, coords, weights,
                                             w1, b1, w2, b2,
                                             cw, betaneg, hegf);

    dim3 grid(M_PTS / TI, N_PTS / JC);
    cg_pairs<<<grid, 256, 0, stream>>>(out_coords, cw, betaneg, ypart);

    cg_finalize<<<(M_PTS * NBASIS) / 256, 256, 0, stream>>>(ypart, hegf,
                                                            (float*)d_out);
}

// Round 10
// 228.651 us; speedup vs baseline: 2.5235x; 2.5235x over previous
//
#include <hip/hip_runtime.h>
#include <hip/hip_bf16.h>

// CoarseGraining: y[i,b] = heg[b] * sum_j exp(-beta[j,b] * d2(i,j)) * wrho[j]
// N = M = 8192, NB = 16, WIDTH = 32. Inputs float32, output float32.
// History: R5 322us (atomics/4.2M), R8 LDS 350us, R9 2x blocks 534us (8.4M
// atomics) -> dur tracks atomic count, same-line L2 RMW serialization is THE
// bottleneck (dur*VALUBusy const ~10.7k across R5/R8/R9).
// R10: one wave per i, lanes split j, shfl_xor butterfly reduce, plain
// stores with heg fused. Zero atomics, no ypart, no memset, no finalize.
// Builtins: exp2 = __builtin_amdgcn_exp2f, log2 = __builtin_amdgcn_logf.

#define N_PTS 8192
#define M_PTS 8192
#define NBASIS 16
#define WIDTH 32

__device__ __forceinline__ float exp2_hw(float x) { return __builtin_amdgcn_exp2f(x); }
__device__ __forceinline__ float log2_hw(float x) { return __builtin_amdgcn_logf(x); }

__device__ __forceinline__ float fast_tanh(float z) {
    float a = fabsf(z);
    float t = __expf(-2.0f * a);
    float r = (1.0f - t) / (1.0f + t);
    return copysignf(r, z);
}

__device__ __forceinline__ float log_cosh_f(float x) {
    float a = fabsf(x);
    return a + __logf(1.0f + __expf(-2.0f * a)) - 0.6931471805599453f;
}

// ---------------- Stage 1: per-source-point quantities ----------------
// cw[j]        = (cx, cy, cz, wrho)
// bnq[q*N + j] = float4{ bn[j][4q..4q+3] }  where bn = -log2(e)*beta
//                (q-plane layout: lane-consecutive j => coalesced dwordx4)
// hegf[0..15]  = log_cosh(embed(0))^1.5
__global__ __launch_bounds__(256)
void cg_prep(const float* __restrict__ rho,
             const float* __restrict__ gamma,
             const float* __restrict__ coords,
             const float* __restrict__ weights,
             const float* __restrict__ w1,
             const float* __restrict__ b1,
             const float* __restrict__ w2,
             const float* __restrict__ b2,
             float4* __restrict__ cw,
             float4* __restrict__ bnq,
             float* __restrict__ hegf)
{
    const float PI_F = 3.14159265358979323846f;
    const float LOG2E = 1.4426950408889634f;

    __shared__ float s_w1[WIDTH], s_b1[WIDTH], s_w2[WIDTH * NBASIS], s_b2[NBASIS];
    int t = threadIdx.x;
    if (t < WIDTH) { s_w1[t] = w1[t]; s_b1[t] = b1[t]; }
    if (t < NBASIS) s_b2[t] = b2[t];
    s_w2[t] = w2[t];
    s_w2[t + 256] = w2[t + 256];
    __syncthreads();

    int j = blockIdx.x * blockDim.x + t;
    if (j < N_PTS) {
        float r = rho[j];
        float g = gamma[j];
        const float c83 = 38.28312007948569f;              // 4*(3*pi^2)^(2/3)
        float r83 = exp2_hw(2.6666666667f * log2_hw(r));   // r^(8/3)
        float s2 = g / (c83 * r83);
        float x = __logf(s2 + 1e-4f);

        float emb[NBASIS];
        #pragma unroll
        for (int b = 0; b < NBASIS; ++b) emb[b] = s_b2[b];
        #pragma unroll 4
        for (int w = 0; w < WIDTH; ++w) {
            float h = fast_tanh(fmaf(x, s_w1[w], s_b1[w]));
            #pragma unroll
            for (int b = 0; b < NBASIS; ++b)
                emb[b] = fmaf(h, s_w2[w * NBASIS + b], emb[b]);
        }
        float pref = PI_F * exp2_hw(0.6666666667f * log2_hw(0.5f * r));
        float scale = -LOG2E * pref;
        #pragma unroll
        for (int q = 0; q < 4; ++q) {
            bnq[q * N_PTS + j] = make_float4(scale * log_cosh_f(emb[4 * q + 0]),
                                             scale * log_cosh_f(emb[4 * q + 1]),
                                             scale * log_cosh_f(emb[4 * q + 2]),
                                             scale * log_cosh_f(emb[4 * q + 3]));
        }

        cw[j] = make_float4(coords[j * 3 + 0],
                            coords[j * 3 + 1],
                            coords[j * 3 + 2],
                            weights[j] * r);
    }

    if (blockIdx.x == 0 && t == 0) {
        float emb0[NBASIS];
        #pragma unroll
        for (int b = 0; b < NBASIS; ++b) emb0[b] = s_b2[b];
        for (int w = 0; w < WIDTH; ++w) {
            float h = fast_tanh(s_b1[w]);   // x = 0
            #pragma unroll
            for (int b = 0; b < NBASIS; ++b)
                emb0[b] = fmaf(h, s_w2[w * NBASIS + b], emb0[b]);
        }
        #pragma unroll
        for (int b = 0; b < NBASIS; ++b) {
            float lc = fmaxf(log_cosh_f(emb0[b]), 0.0f);
            hegf[b] = lc * sqrtf(lc);       // lc^1.5
        }
    }
}

// ---------------- Stage 2: all-pairs, one wave per output point ----------
// wave w owns i=w; lane L handles j = 64k + L (k<128). Butterfly-reduce the
// 16 accumulators across lanes, then lane 0 stores out[i,0..15]*heg.
// 2048 blocks x 4 waves = 8192 waves = 8 waves/SIMD (grid exactly fills HW).
__global__ __launch_bounds__(256, 8)
void cg_pairs(const float* __restrict__ oc,
              const float4* __restrict__ cw,
              const float4* __restrict__ bnq,
              const float* __restrict__ hegf,
              float* __restrict__ out)
{
    int wave = (blockIdx.x << 2) | (threadIdx.x >> 6);   // = i
    int lane = threadIdx.x & 63;
    int i = wave;

    float ox = oc[i * 3 + 0];     // wave-uniform -> s_load
    float oy = oc[i * 3 + 1];
    float oz = oc[i * 3 + 2];

    float acc[NBASIS];
    #pragma unroll
    for (int b = 0; b < NBASIS; ++b) acc[b] = 0.0f;

    for (int k = 0; k < N_PTS / 64; ++k) {
        int j = (k << 6) | lane;                 // lane-consecutive: coalesced
        float4 c = cw[j];
        float dx = ox - c.x;
        float dy = oy - c.y;
        float dz = oz - c.z;
        float d2 = fmaf(dx, dx, fmaf(dy, dy, dz * dz));
        #pragma unroll
        for (int q = 0; q < 4; ++q) {
            float4 b4 = bnq[q * N_PTS + j];      // coalesced dwordx4
            float e0 = exp2_hw(b4.x * d2);
            float e1 = exp2_hw(b4.y * d2);
            float e2 = exp2_hw(b4.z * d2);
            float e3 = exp2_hw(b4.w * d2);
            acc[q * 4 + 0] = fmaf(e0, c.w, acc[q * 4 + 0]);
            acc[q * 4 + 1] = fmaf(e1, c.w, acc[q * 4 + 1]);
            acc[q * 4 + 2] = fmaf(e2, c.w, acc[q * 4 + 2]);
            acc[q * 4 + 3] = fmaf(e3, c.w, acc[q * 4 + 3]);
        }
    }

    // 6-step butterfly over 64 lanes, 16 values
    #pragma unroll
    for (int m = 1; m < 64; m <<= 1) {
        #pragma unroll
        for (int b = 0; b < NBASIS; ++b)
            acc[b] += __shfl_xor(acc[b], m, 64);
    }

    if (lane == 0) {
        float4* o = (float4*)&out[i * NBASIS];
        const float4* hg = (const float4*)hegf;
        #pragma unroll
        for (int q = 0; q < 4; ++q) {
            float4 h = hg[q];
            o[q] = make_float4(acc[q * 4 + 0] * h.x,
                               acc[q * 4 + 1] * h.y,
                               acc[q * 4 + 2] * h.z,
                               acc[q * 4 + 3] * h.w);
        }
    }
}

extern "C" void kernel_launch(void* const* d_in, const int* in_sizes, int n_in,
                              void* d_out, int out_size, void* d_ws, size_t ws_size,
                              hipStream_t stream) {
    const float* rho        = (const float*)d_in[0];
    const float* gamma      = (const float*)d_in[1];
    const float* coords     = (const float*)d_in[2];
    const float* weights    = (const float*)d_in[3];
    const float* out_coords = (const float*)d_in[4];
    const float* w1         = (const float*)d_in[5];
    const float* b1         = (const float*)d_in[6];
    const float* w2         = (const float*)d_in[7];
    const float* b2         = (const float*)d_in[8];

    char* ws = (char*)d_ws;
    // ws layout (640 KiB + 64 B — well under proven 1.1253 MB budget):
    //   cw   : N * float4              = 128 KiB  @ 0
    //   bnq  : 4 planes * N * float4   = 512 KiB  @ 128K
    //   hegf : 16 * float                          @ 640K
    float4* cw   = (float4*)(ws);
    float4* bnq  = (float4*)(ws + (128 << 10));
    float*  hegf = (float*) (ws + (640 << 10));

    cg_prep<<<N_PTS / 256, 256, 0, stream>>>(rho, gamma, coords, weights,
                                             w1, b1, w2, b2,
                                             cw, bnq, hegf);

    cg_pairs<<<M_PTS / 4, 256, 0, stream>>>(out_coords, cw, bnq, hegf,
                                            (float*)d_out);
}

// Round 11
// 208.615 us; speedup vs baseline: 2.7659x; 1.0960x over previous
//
#include <hip/hip_runtime.h>
#include <hip/hip_bf16.h>

// CoarseGraining: y[i,b] = heg[b] * sum_j exp(-beta[j,b] * d2(i,j)) * wrho[j]
// N = M = 8192, NB = 16, WIDTH = 32. Inputs float32, output float32.
// R10 (wave-per-i, no atomics): pairs 183us, VALUBusy 74%, L1<-L2 traffic
// 5.37GB/183us = 29.3 TB/s ~ 85% of L2 ceiling -> L2-BW bound.
// R11: 2 output points per wave -> same j-stream serves 2 i's, traffic /2.
// Trans floor (1.07e9 v_exp) ~55us is the hard floor.
// Builtins: exp2 = __builtin_amdgcn_exp2f, log2 = __builtin_amdgcn_logf.

#define N_PTS 8192
#define M_PTS 8192
#define NBASIS 16
#define WIDTH 32

__device__ __forceinline__ float exp2_hw(float x) { return __builtin_amdgcn_exp2f(x); }
__device__ __forceinline__ float log2_hw(float x) { return __builtin_amdgcn_logf(x); }

__device__ __forceinline__ float fast_tanh(float z) {
    float a = fabsf(z);
    float t = __expf(-2.0f * a);
    float r = (1.0f - t) / (1.0f + t);
    return copysignf(r, z);
}

__device__ __forceinline__ float log_cosh_f(float x) {
    float a = fabsf(x);
    return a + __logf(1.0f + __expf(-2.0f * a)) - 0.6931471805599453f;
}

// ---------------- Stage 1: per-source-point quantities ----------------
// cw[j]        = (cx, cy, cz, wrho)
// bnq[q*N + j] = float4{ bn[j][4q..4q+3] }, bn = -log2(e)*beta (q-plane layout)
// hegf[0..15]  = log_cosh(embed(0))^1.5
__global__ __launch_bounds__(256)
void cg_prep(const float* __restrict__ rho,
             const float* __restrict__ gamma,
             const float* __restrict__ coords,
             const float* __restrict__ weights,
             const float* __restrict__ w1,
             const float* __restrict__ b1,
             const float* __restrict__ w2,
             const float* __restrict__ b2,
             float4* __restrict__ cw,
             float4* __restrict__ bnq,
             float* __restrict__ hegf)
{
    const float PI_F = 3.14159265358979323846f;
    const float LOG2E = 1.4426950408889634f;

    __shared__ float s_w1[WIDTH], s_b1[WIDTH], s_w2[WIDTH * NBASIS], s_b2[NBASIS];
    int t = threadIdx.x;
    if (t < WIDTH) { s_w1[t] = w1[t]; s_b1[t] = b1[t]; }
    if (t < NBASIS) s_b2[t] = b2[t];
    s_w2[t] = w2[t];
    s_w2[t + 256] = w2[t + 256];
    __syncthreads();

    int j = blockIdx.x * blockDim.x + t;
    if (j < N_PTS) {
        float r = rho[j];
        float g = gamma[j];
        const float c83 = 38.28312007948569f;              // 4*(3*pi^2)^(2/3)
        float r83 = exp2_hw(2.6666666667f * log2_hw(r));   // r^(8/3)
        float s2 = g / (c83 * r83);
        float x = __logf(s2 + 1e-4f);

        float emb[NBASIS];
        #pragma unroll
        for (int b = 0; b < NBASIS; ++b) emb[b] = s_b2[b];
        #pragma unroll 4
        for (int w = 0; w < WIDTH; ++w) {
            float h = fast_tanh(fmaf(x, s_w1[w], s_b1[w]));
            #pragma unroll
            for (int b = 0; b < NBASIS; ++b)
                emb[b] = fmaf(h, s_w2[w * NBASIS + b], emb[b]);
        }
        float pref = PI_F * exp2_hw(0.6666666667f * log2_hw(0.5f * r));
        float scale = -LOG2E * pref;
        #pragma unroll
        for (int q = 0; q < 4; ++q) {
            bnq[q * N_PTS + j] = make_float4(scale * log_cosh_f(emb[4 * q + 0]),
                                             scale * log_cosh_f(emb[4 * q + 1]),
                                             scale * log_cosh_f(emb[4 * q + 2]),
                                             scale * log_cosh_f(emb[4 * q + 3]));
        }

        cw[j] = make_float4(coords[j * 3 + 0],
                            coords[j * 3 + 1],
                            coords[j * 3 + 2],
                            weights[j] * r);
    }

    if (blockIdx.x == 0 && t == 0) {
        float emb0[NBASIS];
        #pragma unroll
        for (int b = 0; b < NBASIS; ++b) emb0[b] = s_b2[b];
        for (int w = 0; w < WIDTH; ++w) {
            float h = fast_tanh(s_b1[w]);   // x = 0
            #pragma unroll
            for (int b = 0; b < NBASIS; ++b)
                emb0[b] = fmaf(h, s_w2[w * NBASIS + b], emb0[b]);
        }
        #pragma unroll
        for (int b = 0; b < NBASIS; ++b) {
            float lc = fmaxf(log_cosh_f(emb0[b]), 0.0f);
            hegf[b] = lc * sqrtf(lc);       // lc^1.5
        }
    }
}

// ---------------- Stage 2: all-pairs, TWO output points per wave ----------
// wave w owns i0=2w, i1=2w+1; lane L handles j = 64k+L. Each loaded (cw,bnq)
// feeds both i's -> L2 traffic halved vs R10. Butterfly-reduce 32 accs,
// lane 0 stores both outputs with heg fused.
// grid = 1024 blocks x 4 waves = 4096 waves (4 waves/SIMD).
__global__ __launch_bounds__(256, 4)
void cg_pairs(const float* __restrict__ oc,
              const float4* __restrict__ cw,
              const float4* __restrict__ bnq,
              const float* __restrict__ hegf,
              float* __restrict__ out)
{
    int wave = (blockIdx.x << 2) | (threadIdx.x >> 6);
    int lane = threadIdx.x & 63;
    int i0 = wave << 1;
    int i1 = i0 | 1;

    float ox0 = oc[i0 * 3 + 0], oy0 = oc[i0 * 3 + 1], oz0 = oc[i0 * 3 + 2];
    float ox1 = oc[i1 * 3 + 0], oy1 = oc[i1 * 3 + 1], oz1 = oc[i1 * 3 + 2];

    float acc0[NBASIS], acc1[NBASIS];
    #pragma unroll
    for (int b = 0; b < NBASIS; ++b) { acc0[b] = 0.0f; acc1[b] = 0.0f; }

    #pragma unroll 2
    for (int k = 0; k < N_PTS / 64; ++k) {
        int j = (k << 6) | lane;                 // lane-consecutive: coalesced
        float4 c = cw[j];
        float dx0 = ox0 - c.x, dy0 = oy0 - c.y, dz0 = oz0 - c.z;
        float dx1 = ox1 - c.x, dy1 = oy1 - c.y, dz1 = oz1 - c.z;
        float d20 = fmaf(dx0, dx0, fmaf(dy0, dy0, dz0 * dz0));
        float d21 = fmaf(dx1, dx1, fmaf(dy1, dy1, dz1 * dz1));
        #pragma unroll
        for (int q = 0; q < 4; ++q) {
            float4 b4 = bnq[q * N_PTS + j];      // coalesced dwordx4
            float e00 = exp2_hw(b4.x * d20);
            float e01 = exp2_hw(b4.y * d20);
            float e02 = exp2_hw(b4.z * d20);
            float e03 = exp2_hw(b4.w * d20);
            float e10 = exp2_hw(b4.x * d21);
            float e11 = exp2_hw(b4.y * d21);
            float e12 = exp2_hw(b4.z * d21);
            float e13 = exp2_hw(b4.w * d21);
            acc0[q * 4 + 0] = fmaf(e00, c.w, acc0[q * 4 + 0]);
            acc0[q * 4 + 1] = fmaf(e01, c.w, acc0[q * 4 + 1]);
            acc0[q * 4 + 2] = fmaf(e02, c.w, acc0[q * 4 + 2]);
            acc0[q * 4 + 3] = fmaf(e03, c.w, acc0[q * 4 + 3]);
            acc1[q * 4 + 0] = fmaf(e10, c.w, acc1[q * 4 + 0]);
            acc1[q * 4 + 1] = fmaf(e11, c.w, acc1[q * 4 + 1]);
            acc1[q * 4 + 2] = fmaf(e12, c.w, acc1[q * 4 + 2]);
            acc1[q * 4 + 3] = fmaf(e13, c.w, acc1[q * 4 + 3]);
        }
    }

    // 6-step butterfly over 64 lanes, 32 values
    #pragma unroll
    for (int m = 1; m < 64; m <<= 1) {
        #pragma unroll
        for (int b = 0; b < NBASIS; ++b) {
            acc0[b] += __shfl_xor(acc0[b], m, 64);
            acc1[b] += __shfl_xor(acc1[b], m, 64);
        }
    }

    if (lane == 0) {
        const float4* hg = (const float4*)hegf;
        float4* o0 = (float4*)&out[i0 * NBASIS];
        float4* o1 = (float4*)&out[i1 * NBASIS];
        #pragma unroll
        for (int q = 0; q < 4; ++q) {
            float4 h = hg[q];
            o0[q] = make_float4(acc0[q * 4 + 0] * h.x, acc0[q * 4 + 1] * h.y,
                                acc0[q * 4 + 2] * h.z, acc0[q * 4 + 3] * h.w);
            o1[q] = make_float4(acc1[q * 4 + 0] * h.x, acc1[q * 4 + 1] * h.y,
                                acc1[q * 4 + 2] * h.z, acc1[q * 4 + 3] * h.w);
        }
    }
}

extern "C" void kernel_launch(void* const* d_in, const int* in_sizes, int n_in,
                              void* d_out, int out_size, void* d_ws, size_t ws_size,
                              hipStream_t stream) {
    const float* rho        = (const float*)d_in[0];
    const float* gamma      = (const float*)d_in[1];
    const float* coords     = (const float*)d_in[2];
    const float* weights    = (const float*)d_in[3];
    const float* out_coords = (const float*)d_in[4];
    const float* w1         = (const float*)d_in[5];
    const float* b1         = (const float*)d_in[6];
    const float* w2         = (const float*)d_in[7];
    const float* b2         = (const float*)d_in[8];

    char* ws = (char*)d_ws;
    // ws layout (640 KiB + 64 B — under proven 1.1253 MB budget):
    //   cw   : N * float4              = 128 KiB  @ 0
    //   bnq  : 4 planes * N * float4   = 512 KiB  @ 128K
    //   hegf : 16 * float                          @ 640K
    float4* cw   = (float4*)(ws);
    float4* bnq  = (float4*)(ws + (128 << 10));
    float*  hegf = (float*) (ws + (640 << 10));

    cg_prep<<<N_PTS / 256, 256, 0, stream>>>(rho, gamma, coords, weights,
                                             w1, b1, w2, b2,
                                             cw, bnq, hegf);

    cg_pairs<<<M_PTS / 8, 256, 0, stream>>>(out_coords, cw, bnq, hegf,
                                            (float*)d_out);
}